// Round 14
// baseline (806.987 us; speedup 1.0000x reference)
//
#include <hip/hip_runtime.h>

#define NN 50000
#define NE 1600000
#define C 64            // NOPEN == NUM_OUTPUT == 64
#define NIN 16
#define DTH 0.025f      // dt*H = (1.0/4)*0.1
#define ASC 16.0f       // adjacency weight scale
#define USC 64.0f       // u -> fp8 scale
#define SDIV 16384.0f   // ASC*ASC*USC
#define PSZ 6250        // nodes per partition (8 * 6250 == 50000)
#define PB  128         // blocks per partition for fill
#define SLOT 128        // adjacency slots per node (P(overflow) ~ 1e-8, clamped)

typedef _Float16 f16x2 __attribute__((ext_vector_type(2)));
typedef float f32x2 __attribute__((ext_vector_type(2)));
union U32H2 { uint32_t u; f16x2 h; };

// ---- setup: KN1T, KNcT, K1T, M2 = KN1*KN1^T, KM = KNc*KN1^T ----
__global__ void k_setup(const float* __restrict__ KN1, const float* __restrict__ KNc,
                        const float* __restrict__ K1,
                        float* __restrict__ KN1T, float* __restrict__ KNcT,
                        float* __restrict__ K1T, float* __restrict__ M2s,
                        float* __restrict__ KMs) {
    for (int idx = threadIdx.x; idx < C * C; idx += blockDim.x) {
        int o = idx >> 6, i = idx & 63;
        KN1T[i * C + o] = KN1[o * C + i];
        KNcT[i * C + o] = KNc[o * C + i];
    }
    for (int idx = threadIdx.x; idx < C * NIN; idx += blockDim.x) {
        int o = idx >> 4, i = idx & 15;
        K1T[i * C + o] = K1[o * NIN + i];
    }
    for (int idx = threadIdx.x; idx < C * C; idx += blockDim.x) {
        int p = idx >> 6, o = idx & 63;
        float s1 = 0.f, s2 = 0.f;
        for (int i = 0; i < C; i++) {
            s1 = fmaf(KN1[o * C + i], KN1[p * C + i], s1);
            s2 = fmaf(KNc[o * C + i], KN1[p * C + i], s2);
        }
        M2s[idx] = s1;
        KMs[idx] = s2;
    }
}

// ---- packed counts: low16 = incidence slot counter, high16 = gcn degree ----
__global__ void k_init_pk(unsigned* __restrict__ pk) {
    int n = blockIdx.x * blockDim.x + threadIdx.x;
    if (n < NN) pk[n] = 0x10000u;      // self loop in degree
}

// ---- XCD-partitioned fill: slot = atomic return; raw entry = other | sign<<31 ----
__global__ void k_fillD(const int* __restrict__ iInd, const int* __restrict__ jInd,
                        unsigned* __restrict__ pk, uint32_t* __restrict__ adjp) {
    int p = blockIdx.x & 7;
    int lo = p * PSZ, hi = lo + PSZ;
    int stride = (gridDim.x >> 3) * blockDim.x;
    for (int e = (blockIdx.x >> 3) * blockDim.x + threadIdx.x; e < NE; e += stride) {
        int i = __builtin_nontemporal_load(&iInd[e]);
        int j = __builtin_nontemporal_load(&jInd[e]);
        if (i >= lo && i < hi) {
            unsigned s = atomicAdd(&pk[i], 1u) & 0xFFFFu;          // i-side: slot only
            if (s < SLOT) adjp[((unsigned)i << 7) + s] = (unsigned)j;            // sign 0
        }
        if (j >= lo && j < hi) {
            unsigned s = atomicAdd(&pk[j], 0x10001u) & 0xFFFFu;    // j-side: slot + degree
            if (s < SLOT) adjp[((unsigned)j << 7) + s] = (unsigned)i | 0x80000000u; // sign 1
        }
    }
}
__global__ void k_dinv(const unsigned* __restrict__ pk, float* __restrict__ dinv) {
    int n = blockIdx.x * blockDim.x + threadIdx.x;
    if (n < NN) dinv[n] = 1.0f / sqrtf((float)(pk[n] >> 16));
}
// ---- weight pass: entry -> other | f16(+-ASC*a)<<16 ; zero-pad rows to x32 ----
__global__ void k_weight(const unsigned* __restrict__ pk, const float* __restrict__ dinv,
                         uint32_t* __restrict__ adjp) {
    int idx = blockIdx.x * 256 + threadIdx.x;   // NN*SLOT threads
    int n = idx >> 7, p = idx & (SLOT - 1);
    int cnt = (int)(pk[n] & 0xFFFFu); if (cnt > SLOT) cnt = SLOT;
    int pad = (cnt + 31) & ~31;
    if (p < cnt) {
        uint32_t e = adjp[idx];
        int other = (int)(e & 0xFFFFu);
        float a = ASC * dinv[n] * dinv[other];
        if (e >> 31) a = -a;
        U32H2 t; t.u = (unsigned)other; t.h.y = (_Float16)a;
        adjp[idx] = t.u;
    } else if (p < pad) {
        adjp[idx] = 0u;                          // weight 0 -> contributes nothing
    }
}

// pack 4 consecutive lanes' (USC-scaled) values into fp8x4, lanes lane%4==0 store
static __device__ __forceinline__ void store_u8(uint32_t* __restrict__ u8, int n, int lane, float su) {
    float v1 = __shfl_down(su, 1, 64);
    float v2 = __shfl_down(su, 2, 64);
    float v3 = __shfl_down(su, 3, 64);
    if ((lane & 3) == 0) {
        int p0 = __builtin_amdgcn_cvt_pk_fp8_f32(su, v1, 0, false);
        int p1 = __builtin_amdgcn_cvt_pk_fp8_f32(v2, v3, p0, true);
        u8[n * 16 + (lane >> 2)] = (uint32_t)p1;
    }
}

// ---- opening: x = relu(K1*xn); u0 = KN1*x (f16 + fp8); co = KNc*x ----
__launch_bounds__(256)
__global__ void k_open_u(const float* __restrict__ xn, const float* __restrict__ K1T,
                         const float* __restrict__ KN1T, const float* __restrict__ KNcT,
                         _Float16* __restrict__ u0, uint32_t* __restrict__ u8,
                         float* __restrict__ co) {
    __shared__ float sK1T[NIN * C];
    __shared__ float sKT[C * C];
    __shared__ float sKc[C * C];
    for (int idx = threadIdx.x; idx < NIN * C; idx += 256) sK1T[idx] = K1T[idx];
    for (int idx = threadIdx.x; idx < C * C; idx += 256) { sKT[idx] = KN1T[idx]; sKc[idx] = KNcT[idx]; }
    __syncthreads();
    int wv = threadIdx.x >> 6, lane = threadIdx.x & 63;
    int n = blockIdx.x * 4 + wv;
    float acc = 0.f;
#pragma unroll
    for (int i = 0; i < NIN; i++)
        acc = fmaf(sK1T[i * C + lane], xn[i * NN + n], acc);
    float xr = fmaxf(acc, 0.f);
    float ua = 0.f, oc = 0.f;
    for (int i = 0; i < C; i++) {
        float xi = __shfl(xr, i, 64);
        ua = fmaf(sKT[i * C + lane], xi, ua);
        oc = fmaf(sKc[i * C + lane], xi, oc);
    }
    u0[(size_t)n * C + lane] = (_Float16)ua;
    store_u8(u8, n, lane, ua * USC);
    co[(size_t)n * C + lane] = oc;
}

// per-(w,q) math: lane owns 16 channels (one uint4 = 16 fp8)
#define ACC16(WW, QQ) {                                                       \
    U32H2 aw; aw.u = (WW);                                                    \
    float a_ = (float)aw.h.y;                                                 \
    f32x2 c0_ = __builtin_amdgcn_cvt_pk_f32_fp8((int)(QQ).x, false);          \
    f32x2 c1_ = __builtin_amdgcn_cvt_pk_f32_fp8((int)(QQ).x, true);           \
    f32x2 c2_ = __builtin_amdgcn_cvt_pk_f32_fp8((int)(QQ).y, false);          \
    f32x2 c3_ = __builtin_amdgcn_cvt_pk_f32_fp8((int)(QQ).y, true);           \
    f32x2 c4_ = __builtin_amdgcn_cvt_pk_f32_fp8((int)(QQ).z, false);          \
    f32x2 c5_ = __builtin_amdgcn_cvt_pk_f32_fp8((int)(QQ).z, true);           \
    f32x2 c6_ = __builtin_amdgcn_cvt_pk_f32_fp8((int)(QQ).w, false);          \
    f32x2 c7_ = __builtin_amdgcn_cvt_pk_f32_fp8((int)(QQ).w, true);           \
    acc[0]  = fmaf(a_, fmaxf(a_ * (un[0]  - c0_.x), 0.f), acc[0]);            \
    acc[1]  = fmaf(a_, fmaxf(a_ * (un[1]  - c0_.y), 0.f), acc[1]);            \
    acc[2]  = fmaf(a_, fmaxf(a_ * (un[2]  - c1_.x), 0.f), acc[2]);            \
    acc[3]  = fmaf(a_, fmaxf(a_ * (un[3]  - c1_.y), 0.f), acc[3]);            \
    acc[4]  = fmaf(a_, fmaxf(a_ * (un[4]  - c2_.x), 0.f), acc[4]);            \
    acc[5]  = fmaf(a_, fmaxf(a_ * (un[5]  - c2_.y), 0.f), acc[5]);            \
    acc[6]  = fmaf(a_, fmaxf(a_ * (un[6]  - c3_.x), 0.f), acc[6]);            \
    acc[7]  = fmaf(a_, fmaxf(a_ * (un[7]  - c3_.y), 0.f), acc[7]);            \
    acc[8]  = fmaf(a_, fmaxf(a_ * (un[8]  - c4_.x), 0.f), acc[8]);            \
    acc[9]  = fmaf(a_, fmaxf(a_ * (un[9]  - c4_.y), 0.f), acc[9]);            \
    acc[10] = fmaf(a_, fmaxf(a_ * (un[10] - c5_.x), 0.f), acc[10]);           \
    acc[11] = fmaf(a_, fmaxf(a_ * (un[11] - c5_.y), 0.f), acc[11]);           \
    acc[12] = fmaf(a_, fmaxf(a_ * (un[12] - c6_.x), 0.f), acc[12]);           \
    acc[13] = fmaf(a_, fmaxf(a_ * (un[13] - c6_.y), 0.f), acc[13]);           \
    acc[14] = fmaf(a_, fmaxf(a_ * (un[14] - c7_.x), 0.f), acc[14]);           \
    acc[15] = fmaf(a_, fmaxf(a_ * (un[15] - c7_.y), 0.f), acc[15]);           \
}

// ---- gather core v2: 4 lanes per incidence (uint4 row quarter), 16 incidences/load ----
// ends with s_lane (scaled s for channel = lane) via wave-private LDS transpose
#define GATHER_S_BODY(PKA, ADJP, U8R, STR)                                    \
    const uint4* u8v = (const uint4*)(U8R);                                   \
    uint4 unq = u8v[n * 4 + cg];                                              \
    float un[16];                                                             \
    {                                                                         \
        f32x2 t0 = __builtin_amdgcn_cvt_pk_f32_fp8((int)unq.x, false);        \
        f32x2 t1 = __builtin_amdgcn_cvt_pk_f32_fp8((int)unq.x, true);         \
        f32x2 t2 = __builtin_amdgcn_cvt_pk_f32_fp8((int)unq.y, false);        \
        f32x2 t3 = __builtin_amdgcn_cvt_pk_f32_fp8((int)unq.y, true);         \
        f32x2 t4_ = __builtin_amdgcn_cvt_pk_f32_fp8((int)unq.z, false);       \
        f32x2 t5 = __builtin_amdgcn_cvt_pk_f32_fp8((int)unq.z, true);         \
        f32x2 t6 = __builtin_amdgcn_cvt_pk_f32_fp8((int)unq.w, false);        \
        f32x2 t7 = __builtin_amdgcn_cvt_pk_f32_fp8((int)unq.w, true);         \
        un[0]=t0.x; un[1]=t0.y; un[2]=t1.x; un[3]=t1.y;                       \
        un[4]=t2.x; un[5]=t2.y; un[6]=t3.x; un[7]=t3.y;                       \
        un[8]=t4_.x; un[9]=t4_.y; un[10]=t5.x; un[11]=t5.y;                   \
        un[12]=t6.x; un[13]=t6.y; un[14]=t7.x; un[15]=t7.y;                   \
    }                                                                         \
    int deg = (int)((PKA)[n] & 0xFFFFu); if (deg > SLOT) deg = SLOT;          \
    int degPad = (deg + 31) & ~31;                                            \
    int base = n << 7;                                                        \
    float acc[16];                                                            \
    _Pragma("unroll")                                                         \
    for (int r = 0; r < 16; r++) acc[r] = 0.f;                                \
    for (int c0 = 0; c0 < degPad; c0 += 32) {                                 \
        uint32_t w0 = (ADJP)[base + c0 + t4];                                 \
        uint32_t w1 = (ADJP)[base + c0 + 16 + t4];                            \
        uint4 q0 = u8v[(w0 & 0xFFFFu) * 4 + cg];                              \
        uint4 q1 = u8v[(w1 & 0xFFFFu) * 4 + cg];                              \
        ACC16(w0, q0)                                                         \
        ACC16(w1, q1)                                                         \
    }                                                                         \
    _Pragma("unroll")                                                         \
    for (int r = 0; r < 16; r++) {                                            \
        acc[r] += __shfl_xor(acc[r], 4, 64);                                  \
        acc[r] += __shfl_xor(acc[r], 8, 64);                                  \
        acc[r] += __shfl_xor(acc[r], 16, 64);                                 \
        acc[r] += __shfl_xor(acc[r], 32, 64);                                 \
    }                                                                         \
    if (t4 == 0) {                                                            \
        float4* st = (float4*)&(STR)[wv][cg * 16];                            \
        st[0] = make_float4(acc[0], acc[1], acc[2], acc[3]);                  \
        st[1] = make_float4(acc[4], acc[5], acc[6], acc[7]);                  \
        st[2] = make_float4(acc[8], acc[9], acc[10], acc[11]);                \
        st[3] = make_float4(acc[12], acc[13], acc[14], acc[15]);              \
    }                                                                         \
    float s_lane = (STR)[wv][lane];

// ---- layers 0..2 fused: s = gather; unext = ucur - c*M2*s (f16+fp8); sacc (+)= s ----
__launch_bounds__(256)
__global__ void k_gather_upd(const unsigned* __restrict__ pk, const uint32_t* __restrict__ adjp,
                             const uint32_t* __restrict__ u8r, const _Float16* __restrict__ ucur,
                             const float* __restrict__ M2s, float* __restrict__ sacc,
                             _Float16* __restrict__ unext, uint32_t* __restrict__ u8w, int beta) {
    __shared__ float sM[C * C];
    __shared__ float strans[4][C];
    for (int idx = threadIdx.x; idx < C * C; idx += 256) sM[idx] = M2s[idx];
    __syncthreads();
    int wv = threadIdx.x >> 6, lane = threadIdx.x & 63;
    int t4 = lane >> 2, cg = lane & 3;
    int n = blockIdx.x * 4 + wv;          // 12500*4 == NN exactly
    GATHER_S_BODY(pk, adjp, u8r, strans)
    float du = 0.f;
#pragma unroll
    for (int p = 0; p < C; p++)
        du = fmaf(sM[p * C + lane], __shfl(s_lane, p, 64), du);
    float unew = (float)ucur[(size_t)n * C + lane] - (DTH / SDIV) * du;
    unext[(size_t)n * C + lane] = (_Float16)unew;
    store_u8(u8w, n, lane, unew * USC);
    size_t ix = (size_t)n * C + lane;
    sacc[ix] = beta ? (sacc[ix] + s_lane) : s_lane;
}

// ---- final layer fused: stot = sacc + s; out = log_softmax(co - c*KM*stot) ----
__launch_bounds__(256)
__global__ void k_gather_close(const unsigned* __restrict__ pk, const uint32_t* __restrict__ adjp,
                               const uint32_t* __restrict__ u8r, const float* __restrict__ KMs,
                               const float* __restrict__ sacc, const float* __restrict__ co,
                               float* __restrict__ out) {
    __shared__ float sKM[C * C];
    __shared__ float strans[4][C];
    for (int idx = threadIdx.x; idx < C * C; idx += 256) sKM[idx] = KMs[idx];
    __syncthreads();
    int wv = threadIdx.x >> 6, lane = threadIdx.x & 63;
    int t4 = lane >> 2, cg = lane & 3;
    int n = blockIdx.x * 4 + wv;
    GATHER_S_BODY(pk, adjp, u8r, strans)
    float stot = s_lane + sacc[(size_t)n * C + lane];
    float dx = 0.f;
#pragma unroll
    for (int p = 0; p < C; p++)
        dx = fmaf(sKM[p * C + lane], __shfl(stot, p, 64), dx);
    float o = co[(size_t)n * C + lane] - (DTH / SDIV) * dx;
    float m = o;
#pragma unroll
    for (int off2 = 32; off2; off2 >>= 1) m = fmaxf(m, __shfl_xor(m, off2, 64));
    float sum = expf(o - m);
#pragma unroll
    for (int off2 = 32; off2; off2 >>= 1) sum += __shfl_xor(sum, off2, 64);
    out[(size_t)n * C + lane] = o - m - logf(sum);
}

extern "C" void kernel_launch(void* const* d_in, const int* in_sizes, int n_in,
                              void* d_out, int out_size, void* d_ws, size_t ws_size,
                              hipStream_t stream) {
    (void)in_sizes; (void)n_in; (void)out_size; (void)ws_size;
    const float* xn   = (const float*)d_in[0];
    const int* iInd   = (const int*)d_in[1];
    const int* jInd   = (const int*)d_in[2];
    // d_in[3] = n_nodes scalar (fixed 50000)
    const float* K1   = (const float*)d_in[4];
    const float* KN1  = (const float*)d_in[5];
    const float* KNc  = (const float*)d_in[6];
    float* out = (float*)d_out;

    char* base = (char*)d_ws;
    size_t off = 0;
    auto alloc = [&](size_t bytes) { char* p = base + off; off = (off + bytes + 255) & ~(size_t)255; return p; };
    float* KN1T = (float*)alloc(C * C * 4);
    float* KNcT = (float*)alloc(C * C * 4);
    float* K1T  = (float*)alloc(NIN * C * 4);
    float* M2s  = (float*)alloc(C * C * 4);
    float* KMs  = (float*)alloc(C * C * 4);
    unsigned* pk = (unsigned*)alloc(NN * 4);
    float* dinv = (float*)alloc(NN * 4);
    float* co   = (float*)alloc((size_t)NN * C * 4);       // 12.8 MB
    float* sacc = (float*)alloc((size_t)NN * C * 4);       // 12.8 MB
    _Float16* ua = (_Float16*)alloc((size_t)NN * C * 2);   // 6.4 MB
    _Float16* ub = (_Float16*)alloc((size_t)NN * C * 2);   // 6.4 MB
    uint32_t* u8a = (uint32_t*)alloc((size_t)NN * 16 * 4); // 3.2 MB
    uint32_t* u8b = (uint32_t*)alloc((size_t)NN * 16 * 4); // 3.2 MB
    uint32_t* adjp = (uint32_t*)alloc((size_t)NN * SLOT * 4); // 25.6 MB

    // prolog: one-pass slotted fill, then weights
    k_setup<<<1, 256, 0, stream>>>(KN1, KNc, K1, KN1T, KNcT, K1T, M2s, KMs);
    k_init_pk<<<(NN + 255) / 256, 256, 0, stream>>>(pk);
    k_fillD<<<8 * PB, 256, 0, stream>>>(iInd, jInd, pk, adjp);
    k_dinv<<<(NN + 255) / 256, 256, 0, stream>>>(pk, dinv);
    k_weight<<<(NN * SLOT) / 256, 256, 0, stream>>>(pk, dinv, adjp);

    // opening: u0 (f16 + fp8) and co = KNc*x0
    k_open_u<<<NN / 4, 256, 0, stream>>>(xn, K1T, KN1T, KNcT, ua, u8a, co);

    const int GB = NN / 4;    // 12500 blocks, one node per wave
    k_gather_upd<<<GB, 256, 0, stream>>>(pk, adjp, u8a, ua, M2s, sacc, ub, u8b, 0);
    k_gather_upd<<<GB, 256, 0, stream>>>(pk, adjp, u8b, ub, M2s, sacc, ua, u8a, 1);
    k_gather_upd<<<GB, 256, 0, stream>>>(pk, adjp, u8a, ua, M2s, sacc, ub, u8b, 1);
    k_gather_close<<<GB, 256, 0, stream>>>(pk, adjp, u8b, KMs, sacc, co, out);
}

// Round 15
// 674.728 us; speedup vs baseline: 1.1960x; 1.1960x over previous
//
#include <hip/hip_runtime.h>

#define NN 50000
#define NE 1600000
#define C 64            // NOPEN == NUM_OUTPUT == 64
#define NIN 16
#define DTH 0.025f      // dt*H = (1.0/4)*0.1
#define ASC 16.0f       // adjacency weight scale
#define USC 64.0f       // u -> fp8 scale
#define SDIV 16384.0f   // ASC*ASC*USC
#define PSZ 6250        // nodes per partition (8 * 6250 == 50000)
#define PB  256         // blocks per partition for fill (2048 total -> 32 waves/CU)
#define SLOT 128        // adjacency slots per node (P(overflow) ~ 1e-8, clamped)

typedef _Float16 f16x2 __attribute__((ext_vector_type(2)));
typedef float f32x2 __attribute__((ext_vector_type(2)));
union U32H2 { uint32_t u; f16x2 h; };

// ---- setup: KN1T, KNcT, K1T, M2 = KN1*KN1^T, KM = KNc*KN1^T ----
__global__ void k_setup(const float* __restrict__ KN1, const float* __restrict__ KNc,
                        const float* __restrict__ K1,
                        float* __restrict__ KN1T, float* __restrict__ KNcT,
                        float* __restrict__ K1T, float* __restrict__ M2s,
                        float* __restrict__ KMs) {
    for (int idx = threadIdx.x; idx < C * C; idx += blockDim.x) {
        int o = idx >> 6, i = idx & 63;
        KN1T[i * C + o] = KN1[o * C + i];
        KNcT[i * C + o] = KNc[o * C + i];
    }
    for (int idx = threadIdx.x; idx < C * NIN; idx += blockDim.x) {
        int o = idx >> 4, i = idx & 15;
        K1T[i * C + o] = K1[o * NIN + i];
    }
    for (int idx = threadIdx.x; idx < C * C; idx += blockDim.x) {
        int p = idx >> 6, o = idx & 63;
        float s1 = 0.f, s2 = 0.f;
        for (int i = 0; i < C; i++) {
            s1 = fmaf(KN1[o * C + i], KN1[p * C + i], s1);
            s2 = fmaf(KNc[o * C + i], KN1[p * C + i], s2);
        }
        M2s[idx] = s1;
        KMs[idx] = s2;
    }
}

// ---- packed counts: low16 = incidence slot counter, high16 = gcn degree ----
__global__ void k_init_pk(unsigned* __restrict__ pk) {
    int n = blockIdx.x * blockDim.x + threadIdx.x;
    if (n < NN) pk[n] = 0x10000u;      // self loop in degree
}

// ---- XCD-partitioned fill, 2-edge unroll for atomic overlap ----
__global__ void k_fillD(const int* __restrict__ iInd, const int* __restrict__ jInd,
                        unsigned* __restrict__ pk, uint32_t* __restrict__ adjp) {
    int p = blockIdx.x & 7;
    int lo = p * PSZ, hi = lo + PSZ;
    int stride = (gridDim.x >> 3) * blockDim.x;
    int e0 = (blockIdx.x >> 3) * blockDim.x + threadIdx.x;
    for (int e = e0; e < NE; e += 2 * stride) {
        int i0 = __builtin_nontemporal_load(&iInd[e]);
        int j0 = __builtin_nontemporal_load(&jInd[e]);
        int e1 = e + stride;
        int i1 = -1, j1 = -1;
        if (e1 < NE) {
            i1 = __builtin_nontemporal_load(&iInd[e1]);
            j1 = __builtin_nontemporal_load(&jInd[e1]);
        }
        if (i0 >= lo && i0 < hi) {
            unsigned s = atomicAdd(&pk[i0], 1u) & 0xFFFFu;
            if (s < SLOT) adjp[((unsigned)i0 << 7) + s] = (unsigned)j0;
        }
        if (j0 >= lo && j0 < hi) {
            unsigned s = atomicAdd(&pk[j0], 0x10001u) & 0xFFFFu;
            if (s < SLOT) adjp[((unsigned)j0 << 7) + s] = (unsigned)i0 | 0x80000000u;
        }
        if (i1 >= lo && i1 < hi) {
            unsigned s = atomicAdd(&pk[i1], 1u) & 0xFFFFu;
            if (s < SLOT) adjp[((unsigned)i1 << 7) + s] = (unsigned)j1;
        }
        if (j1 >= lo && j1 < hi) {
            unsigned s = atomicAdd(&pk[j1], 0x10001u) & 0xFFFFu;
            if (s < SLOT) adjp[((unsigned)j1 << 7) + s] = (unsigned)i1 | 0x80000000u;
        }
    }
}
__global__ void k_dinv(const unsigned* __restrict__ pk, float* __restrict__ dinv) {
    int n = blockIdx.x * blockDim.x + threadIdx.x;
    if (n < NN) dinv[n] = 1.0f / sqrtf((float)(pk[n] >> 16));
}
// ---- weight pass: entry -> other | f16(+-ASC*a)<<16 ; zero-pad rows to x32 ----
__global__ void k_weight(const unsigned* __restrict__ pk, const float* __restrict__ dinv,
                         uint32_t* __restrict__ adjp) {
    int idx = blockIdx.x * 256 + threadIdx.x;   // NN*SLOT threads
    int n = idx >> 7, p = idx & (SLOT - 1);
    int cnt = (int)(pk[n] & 0xFFFFu); if (cnt > SLOT) cnt = SLOT;
    int pad = (cnt + 31) & ~31;
    if (p < cnt) {
        uint32_t e = adjp[idx];
        int other = (int)(e & 0xFFFFu);
        float a = ASC * dinv[n] * dinv[other];
        if (e >> 31) a = -a;
        U32H2 t; t.u = (unsigned)other; t.h.y = (_Float16)a;
        adjp[idx] = t.u;
    } else if (p < pad) {
        adjp[idx] = 0u;                          // weight 0 -> contributes nothing
    }
}

// pack 4 consecutive lanes' (USC-scaled) values into fp8x4, lanes lane%4==0 store
static __device__ __forceinline__ void store_u8(uint32_t* __restrict__ u8, int n, int lane, float su) {
    float v1 = __shfl_down(su, 1, 64);
    float v2 = __shfl_down(su, 2, 64);
    float v3 = __shfl_down(su, 3, 64);
    if ((lane & 3) == 0) {
        int p0 = __builtin_amdgcn_cvt_pk_fp8_f32(su, v1, 0, false);
        int p1 = __builtin_amdgcn_cvt_pk_fp8_f32(v2, v3, p0, true);
        u8[n * 16 + (lane >> 2)] = (uint32_t)p1;
    }
}

// ---- opening: x = relu(K1*xn); u0 = KN1*x (f16 + fp8); co = KNc*x ----
__launch_bounds__(256)
__global__ void k_open_u(const float* __restrict__ xn, const float* __restrict__ K1T,
                         const float* __restrict__ KN1T, const float* __restrict__ KNcT,
                         _Float16* __restrict__ u0, uint32_t* __restrict__ u8,
                         float* __restrict__ co) {
    __shared__ float sK1T[NIN * C];
    __shared__ float sKT[C * C];
    __shared__ float sKc[C * C];
    for (int idx = threadIdx.x; idx < NIN * C; idx += 256) sK1T[idx] = K1T[idx];
    for (int idx = threadIdx.x; idx < C * C; idx += 256) { sKT[idx] = KN1T[idx]; sKc[idx] = KNcT[idx]; }
    __syncthreads();
    int wv = threadIdx.x >> 6, lane = threadIdx.x & 63;
    int n = blockIdx.x * 4 + wv;
    float acc = 0.f;
#pragma unroll
    for (int i = 0; i < NIN; i++)
        acc = fmaf(sK1T[i * C + lane], xn[i * NN + n], acc);
    float xr = fmaxf(acc, 0.f);
    float ua = 0.f, oc = 0.f;
    for (int i = 0; i < C; i++) {
        float xi = __shfl(xr, i, 64);
        ua = fmaf(sKT[i * C + lane], xi, ua);
        oc = fmaf(sKc[i * C + lane], xi, oc);
    }
    u0[(size_t)n * C + lane] = (_Float16)ua;
    store_u8(u8, n, lane, ua * USC);
    co[(size_t)n * C + lane] = oc;
}

#define ACCR(WW, QQ, A0, A1, A2, A3, U0, U1, U2, U3) {                        \
    U32H2 aw; aw.u = (WW);                                                    \
    float a_ = (float)aw.h.y;                                                 \
    f32x2 lo_ = __builtin_amdgcn_cvt_pk_f32_fp8((int)(QQ), false);            \
    f32x2 hi_ = __builtin_amdgcn_cvt_pk_f32_fp8((int)(QQ), true);             \
    A0 = fmaf(a_, fmaxf(a_ * ((U0) - lo_.x), 0.f), A0);                       \
    A1 = fmaf(a_, fmaxf(a_ * ((U1) - lo_.y), 0.f), A1);                       \
    A2 = fmaf(a_, fmaxf(a_ * ((U2) - hi_.x), 0.f), A2);                       \
    A3 = fmaf(a_, fmaxf(a_ * ((U3) - hi_.y), 0.f), A3);                       \
}

// ---- two-node interleaved gather core (round-13 per-incidence layout) ----
// yields sA_lane, sB_lane (scaled s for channel = lane) for nodes nA, nB = nA+1
#define GATHER2_BODY(PKA, ADJP, U8R)                                          \
    uint32_t unqA = (U8R)[nA * 16 + li];                                      \
    uint32_t unqB = (U8R)[nB * 16 + li];                                      \
    f32x2 alo = __builtin_amdgcn_cvt_pk_f32_fp8((int)unqA, false);            \
    f32x2 ahi = __builtin_amdgcn_cvt_pk_f32_fp8((int)unqA, true);             \
    f32x2 blo = __builtin_amdgcn_cvt_pk_f32_fp8((int)unqB, false);            \
    f32x2 bhi = __builtin_amdgcn_cvt_pk_f32_fp8((int)unqB, true);             \
    float uA0 = alo.x, uA1 = alo.y, uA2 = ahi.x, uA3 = ahi.y;                 \
    float uB0 = blo.x, uB1 = blo.y, uB2 = bhi.x, uB3 = bhi.y;                 \
    int degA = (int)((PKA)[nA] & 0xFFFFu); if (degA > SLOT) degA = SLOT;      \
    int degB = (int)((PKA)[nB] & 0xFFFFu); if (degB > SLOT) degB = SLOT;      \
    int padA = (degA + 31) & ~31, padB = (degB + 31) & ~31;                   \
    int baseA = nA << 7, baseB = nB << 7;                                     \
    int maxPad = padA > padB ? padA : padB;                                   \
    float aA0 = 0.f, aA1 = 0.f, aA2 = 0.f, aA3 = 0.f;                         \
    float aB0 = 0.f, aB1 = 0.f, aB2 = 0.f, aB3 = 0.f;                         \
    for (int c0 = 0; c0 < maxPad; c0 += 32) {                                 \
        uint32_t wA[8], qA[8], wB[8], qB[8];                                  \
        bool dA = c0 < padA, dB = c0 < padB;                                  \
        if (dA) {                                                             \
            _Pragma("unroll")                                                 \
            for (int r = 0; r < 8; r++) wA[r] = (ADJP)[baseA + c0 + r * 4 + g]; \
        }                                                                     \
        if (dB) {                                                             \
            _Pragma("unroll")                                                 \
            for (int r = 0; r < 8; r++) wB[r] = (ADJP)[baseB + c0 + r * 4 + g]; \
        }                                                                     \
        if (dA) {                                                             \
            _Pragma("unroll")                                                 \
            for (int r = 0; r < 8; r++) qA[r] = (U8R)[(wA[r] & 0xFFFFu) * 16 + li]; \
        }                                                                     \
        if (dB) {                                                             \
            _Pragma("unroll")                                                 \
            for (int r = 0; r < 8; r++) qB[r] = (U8R)[(wB[r] & 0xFFFFu) * 16 + li]; \
        }                                                                     \
        if (dA) {                                                             \
            _Pragma("unroll")                                                 \
            for (int r = 0; r < 8; r++) ACCR(wA[r], qA[r], aA0, aA1, aA2, aA3, uA0, uA1, uA2, uA3) \
        }                                                                     \
        if (dB) {                                                             \
            _Pragma("unroll")                                                 \
            for (int r = 0; r < 8; r++) ACCR(wB[r], qB[r], aB0, aB1, aB2, aB3, uB0, uB1, uB2, uB3) \
        }                                                                     \
    }                                                                         \
    aA0 += __shfl_xor(aA0, 16, 64); aA0 += __shfl_xor(aA0, 32, 64);           \
    aA1 += __shfl_xor(aA1, 16, 64); aA1 += __shfl_xor(aA1, 32, 64);           \
    aA2 += __shfl_xor(aA2, 16, 64); aA2 += __shfl_xor(aA2, 32, 64);           \
    aA3 += __shfl_xor(aA3, 16, 64); aA3 += __shfl_xor(aA3, 32, 64);           \
    aB0 += __shfl_xor(aB0, 16, 64); aB0 += __shfl_xor(aB0, 32, 64);           \
    aB1 += __shfl_xor(aB1, 16, 64); aB1 += __shfl_xor(aB1, 32, 64);           \
    aB2 += __shfl_xor(aB2, 16, 64); aB2 += __shfl_xor(aB2, 32, 64);           \
    aB3 += __shfl_xor(aB3, 16, 64); aB3 += __shfl_xor(aB3, 32, 64);           \
    float rA0 = __shfl(aA0, lane >> 2, 64), rA1 = __shfl(aA1, lane >> 2, 64); \
    float rA2 = __shfl(aA2, lane >> 2, 64), rA3 = __shfl(aA3, lane >> 2, 64); \
    float rB0 = __shfl(aB0, lane >> 2, 64), rB1 = __shfl(aB1, lane >> 2, 64); \
    float rB2 = __shfl(aB2, lane >> 2, 64), rB3 = __shfl(aB3, lane >> 2, 64); \
    float sA_lane = (lane & 2) ? ((lane & 1) ? rA3 : rA2)                     \
                               : ((lane & 1) ? rA1 : rA0);                    \
    float sB_lane = (lane & 2) ? ((lane & 1) ? rB3 : rB2)                     \
                               : ((lane & 1) ? rB1 : rB0);

// ---- layers 0..2 fused: s = gather; unext = ucur - c*M2*s (f16+fp8); sacc (+)= s ----
__launch_bounds__(256)
__global__ void k_gather_upd(const unsigned* __restrict__ pk, const uint32_t* __restrict__ adjp,
                             const uint32_t* __restrict__ u8r, const _Float16* __restrict__ ucur,
                             const float* __restrict__ M2s, float* __restrict__ sacc,
                             _Float16* __restrict__ unext, uint32_t* __restrict__ u8w, int beta) {
    __shared__ float sM[C * C];
    for (int idx = threadIdx.x; idx < C * C; idx += 256) sM[idx] = M2s[idx];
    __syncthreads();
    int wv = threadIdx.x >> 6, lane = threadIdx.x & 63;
    int g = lane >> 4, li = lane & 15;
    int nA = (blockIdx.x * 4 + wv) * 2;   // 6250 blocks * 4 waves * 2 nodes = 50000
    int nB = nA + 1;
    GATHER2_BODY(pk, adjp, u8r)
    float duA = 0.f, duB = 0.f;
#pragma unroll
    for (int p = 0; p < C; p++) {
        float m = sM[p * C + lane];
        duA = fmaf(m, __shfl(sA_lane, p, 64), duA);
        duB = fmaf(m, __shfl(sB_lane, p, 64), duB);
    }
    float unewA = (float)ucur[(size_t)nA * C + lane] - (DTH / SDIV) * duA;
    float unewB = (float)ucur[(size_t)nB * C + lane] - (DTH / SDIV) * duB;
    unext[(size_t)nA * C + lane] = (_Float16)unewA;
    unext[(size_t)nB * C + lane] = (_Float16)unewB;
    store_u8(u8w, nA, lane, unewA * USC);
    store_u8(u8w, nB, lane, unewB * USC);
    size_t ixA = (size_t)nA * C + lane, ixB = (size_t)nB * C + lane;
    sacc[ixA] = beta ? (sacc[ixA] + sA_lane) : sA_lane;
    sacc[ixB] = beta ? (sacc[ixB] + sB_lane) : sB_lane;
}

// ---- final layer fused: stot = sacc + s; out = log_softmax(co - c*KM*stot) ----
__launch_bounds__(256)
__global__ void k_gather_close(const unsigned* __restrict__ pk, const uint32_t* __restrict__ adjp,
                               const uint32_t* __restrict__ u8r, const float* __restrict__ KMs,
                               const float* __restrict__ sacc, const float* __restrict__ co,
                               float* __restrict__ out) {
    __shared__ float sKM[C * C];
    for (int idx = threadIdx.x; idx < C * C; idx += 256) sKM[idx] = KMs[idx];
    __syncthreads();
    int wv = threadIdx.x >> 6, lane = threadIdx.x & 63;
    int g = lane >> 4, li = lane & 15;
    int nA = (blockIdx.x * 4 + wv) * 2;
    int nB = nA + 1;
    GATHER2_BODY(pk, adjp, u8r)
    float stotA = sA_lane + sacc[(size_t)nA * C + lane];
    float stotB = sB_lane + sacc[(size_t)nB * C + lane];
    float dxA = 0.f, dxB = 0.f;
#pragma unroll
    for (int p = 0; p < C; p++) {
        float m = sKM[p * C + lane];
        dxA = fmaf(m, __shfl(stotA, p, 64), dxA);
        dxB = fmaf(m, __shfl(stotB, p, 64), dxB);
    }
    float oA = co[(size_t)nA * C + lane] - (DTH / SDIV) * dxA;
    float oB = co[(size_t)nB * C + lane] - (DTH / SDIV) * dxB;
    float mA = oA, mB = oB;
#pragma unroll
    for (int off2 = 32; off2; off2 >>= 1) {
        mA = fmaxf(mA, __shfl_xor(mA, off2, 64));
        mB = fmaxf(mB, __shfl_xor(mB, off2, 64));
    }
    float sumA = expf(oA - mA), sumB = expf(oB - mB);
#pragma unroll
    for (int off2 = 32; off2; off2 >>= 1) {
        sumA += __shfl_xor(sumA, off2, 64);
        sumB += __shfl_xor(sumB, off2, 64);
    }
    out[(size_t)nA * C + lane] = oA - mA - logf(sumA);
    out[(size_t)nB * C + lane] = oB - mB - logf(sumB);
}

extern "C" void kernel_launch(void* const* d_in, const int* in_sizes, int n_in,
                              void* d_out, int out_size, void* d_ws, size_t ws_size,
                              hipStream_t stream) {
    (void)in_sizes; (void)n_in; (void)out_size; (void)ws_size;
    const float* xn   = (const float*)d_in[0];
    const int* iInd   = (const int*)d_in[1];
    const int* jInd   = (const int*)d_in[2];
    // d_in[3] = n_nodes scalar (fixed 50000)
    const float* K1   = (const float*)d_in[4];
    const float* KN1  = (const float*)d_in[5];
    const float* KNc  = (const float*)d_in[6];
    float* out = (float*)d_out;

    char* base = (char*)d_ws;
    size_t off = 0;
    auto alloc = [&](size_t bytes) { char* p = base + off; off = (off + bytes + 255) & ~(size_t)255; return p; };
    float* KN1T = (float*)alloc(C * C * 4);
    float* KNcT = (float*)alloc(C * C * 4);
    float* K1T  = (float*)alloc(NIN * C * 4);
    float* M2s  = (float*)alloc(C * C * 4);
    float* KMs  = (float*)alloc(C * C * 4);
    unsigned* pk = (unsigned*)alloc(NN * 4);
    float* dinv = (float*)alloc(NN * 4);
    float* co   = (float*)alloc((size_t)NN * C * 4);       // 12.8 MB
    float* sacc = (float*)alloc((size_t)NN * C * 4);       // 12.8 MB
    _Float16* ua = (_Float16*)alloc((size_t)NN * C * 2);   // 6.4 MB
    _Float16* ub = (_Float16*)alloc((size_t)NN * C * 2);   // 6.4 MB
    uint32_t* u8a = (uint32_t*)alloc((size_t)NN * 16 * 4); // 3.2 MB
    uint32_t* u8b = (uint32_t*)alloc((size_t)NN * 16 * 4); // 3.2 MB
    uint32_t* adjp = (uint32_t*)alloc((size_t)NN * SLOT * 4); // 25.6 MB

    // prolog: one-pass slotted fill, then weights
    k_setup<<<1, 256, 0, stream>>>(KN1, KNc, K1, KN1T, KNcT, K1T, M2s, KMs);
    k_init_pk<<<(NN + 255) / 256, 256, 0, stream>>>(pk);
    k_fillD<<<8 * PB, 256, 0, stream>>>(iInd, jInd, pk, adjp);
    k_dinv<<<(NN + 255) / 256, 256, 0, stream>>>(pk, dinv);
    k_weight<<<(NN * SLOT) / 256, 256, 0, stream>>>(pk, dinv, adjp);

    // opening: u0 (f16 + fp8) and co = KNc*x0
    k_open_u<<<NN / 4, 256, 0, stream>>>(xn, K1T, KN1T, KNcT, ua, u8a, co);

    const int GB = NN / 8;    // 6250 blocks, two nodes per wave
    k_gather_upd<<<GB, 256, 0, stream>>>(pk, adjp, u8a, ua, M2s, sacc, ub, u8b, 0);
    k_gather_upd<<<GB, 256, 0, stream>>>(pk, adjp, u8b, ub, M2s, sacc, ua, u8a, 1);
    k_gather_upd<<<GB, 256, 0, stream>>>(pk, adjp, u8a, ua, M2s, sacc, ub, u8b, 1);
    k_gather_close<<<GB, 256, 0, stream>>>(pk, adjp, u8b, KMs, sacc, co, out);
}

// Round 16
// 597.090 us; speedup vs baseline: 1.3515x; 1.1300x over previous
//
#include <hip/hip_runtime.h>

#define NN 50000
#define NE 1600000
#define C 64            // NOPEN == NUM_OUTPUT == 64
#define NIN 16
#define DTH 0.025f      // dt*H = (1.0/4)*0.1
#define ASC 16.0f       // adjacency weight scale
#define USC 64.0f       // u -> fp8 scale
#define SDIV 16384.0f   // ASC*ASC*USC
#define SLOT 128        // adjacency slots per node (P(overflow) ~ 1e-8, clamped)

// two-phase binned CSR build
#define NB2 128         // node-range bins (each owned by one phase-B block)
#define NPB 391         // nodes per bin (128*391 = 50048 >= NN)
#define CAP 32768       // stg capacity per bin (avg 25000, +49 sigma)
#define ABLK 1024       // phase-A blocks
#define EPB 1563        // edges per phase-A block (1024*1563 >= NE)
#define RND 1536        // edges per staging round (256 thr * 6)

typedef _Float16 f16x2 __attribute__((ext_vector_type(2)));
typedef float f32x2 __attribute__((ext_vector_type(2)));
union U32H2 { uint32_t u; f16x2 h; };

// ---- setup: KN1T, KNcT, K1T, M2 = KN1*KN1^T, KM = KNc*KN1^T ; zero gcur ----
__global__ void k_setup(const float* __restrict__ KN1, const float* __restrict__ KNc,
                        const float* __restrict__ K1,
                        float* __restrict__ KN1T, float* __restrict__ KNcT,
                        float* __restrict__ K1T, float* __restrict__ M2s,
                        float* __restrict__ KMs, int* __restrict__ gcur) {
    if (threadIdx.x < NB2) gcur[threadIdx.x] = 0;
    for (int idx = threadIdx.x; idx < C * C; idx += blockDim.x) {
        int o = idx >> 6, i = idx & 63;
        KN1T[i * C + o] = KN1[o * C + i];
        KNcT[i * C + o] = KNc[o * C + i];
    }
    for (int idx = threadIdx.x; idx < C * NIN; idx += blockDim.x) {
        int o = idx >> 4, i = idx & 15;
        K1T[i * C + o] = K1[o * NIN + i];
    }
    for (int idx = threadIdx.x; idx < C * C; idx += blockDim.x) {
        int p = idx >> 6, o = idx & 63;
        float s1 = 0.f, s2 = 0.f;
        for (int i = 0; i < C; i++) {
            s1 = fmaf(KN1[o * C + i], KN1[p * C + i], s1);
            s2 = fmaf(KNc[o * C + i], KN1[p * C + i], s2);
        }
        M2s[idx] = s1;
        KMs[idx] = s2;
    }
}

// ---- phase A: LDS-binned scatter of incidences into 128 per-bin streams ----
__launch_bounds__(256)
__global__ void k_binA(const int* __restrict__ iInd, const int* __restrict__ jInd,
                       int* __restrict__ gcur, uint32_t* __restrict__ stg) {
    __shared__ uint32_t bins[NB2][64];
    __shared__ int bcnt[NB2];
    int tid = threadIdx.x;
    int eBeg = blockIdx.x * EPB;
    int eEnd = eBeg + EPB; if (eEnd > NE) eEnd = NE;
    for (int rb = eBeg; rb < eEnd; rb += RND) {
        for (int b = tid; b < NB2; b += 256) bcnt[b] = 0;
        __syncthreads();
        int rEnd = rb + RND; if (rEnd > eEnd) rEnd = eEnd;
        for (int e = rb + tid; e < rEnd; e += 256) {
            int i = __builtin_nontemporal_load(&iInd[e]);
            int j = __builtin_nontemporal_load(&jInd[e]);
            {   // i-side: target=i, sign 0
                int b = (unsigned)i / NPB;
                uint32_t ent = ((unsigned)(i - b * NPB) << 17) | (unsigned)j;
                int pos = atomicAdd(&bcnt[b], 1);
                if (pos < 64) bins[b][pos] = ent;
                else { int gp = atomicAdd(&gcur[b], 1); stg[(size_t)b * CAP + gp] = ent; }
            }
            {   // j-side: target=j, sign 1
                int b = (unsigned)j / NPB;
                uint32_t ent = ((unsigned)(j - b * NPB) << 17) | 0x10000u | (unsigned)i;
                int pos = atomicAdd(&bcnt[b], 1);
                if (pos < 64) bins[b][pos] = ent;
                else { int gp = atomicAdd(&gcur[b], 1); stg[(size_t)b * CAP + gp] = ent; }
            }
        }
        __syncthreads();
        for (int b = tid; b < NB2; b += 256) {   // 128 flusher threads
            int c = bcnt[b]; if (c > 64) c = 64;
            if (c > 0) {
                int gb = atomicAdd(&gcur[b], c);
                for (int k = 0; k < c; k++)
                    stg[(size_t)b * CAP + gb + k] = bins[b][k];
            }
        }
        __syncthreads();
    }
}

// ---- phase B: per-bin exclusive slot assignment (LDS counters, no device atomics) ----
// writes raw adj entry = other | sign<<31 ; pk[n] = (deg)<<16 | cnt
__launch_bounds__(1024)
__global__ void k_binB(const int* __restrict__ gcur, const uint32_t* __restrict__ stg,
                       unsigned* __restrict__ pk, uint32_t* __restrict__ adjp) {
    __shared__ unsigned lcnt[NPB];   // low16 = slot count, high16 = j-side count
    int b = blockIdx.x, tid = threadIdx.x;
    for (int t = tid; t < NPB; t += 1024) lcnt[t] = 0;
    __syncthreads();
    int cnt = gcur[b];
    int n0 = b * NPB;
    for (int k = tid; k < cnt; k += 1024) {
        uint32_t ent = stg[(size_t)b * CAP + k];
        int tl = (int)(ent >> 17);
        unsigned sign = (ent >> 16) & 1u;
        unsigned other = ent & 0xFFFFu;
        unsigned ret = atomicAdd(&lcnt[tl], 1u + (sign << 16));
        unsigned slot = ret & 0xFFFFu;
        if (slot < SLOT) adjp[(((unsigned)(n0 + tl)) << 7) + slot] = other | (sign << 31);
    }
    __syncthreads();
    for (int t = tid; t < NPB; t += 1024) {
        int n = n0 + t;
        if (n < NN) {
            unsigned v = lcnt[t];
            unsigned c = v & 0xFFFFu; if (c > SLOT) c = SLOT;
            pk[n] = (((v >> 16) + 1u) << 16) | c;   // degree = j-count + self loop
        }
    }
}

__global__ void k_dinv(const unsigned* __restrict__ pk, float* __restrict__ dinv) {
    int n = blockIdx.x * blockDim.x + threadIdx.x;
    if (n < NN) dinv[n] = 1.0f / sqrtf((float)(pk[n] >> 16));
}
// ---- weight pass: entry -> other | f16(+-ASC*a)<<16 ; zero-pad rows to x32 ----
__global__ void k_weight(const unsigned* __restrict__ pk, const float* __restrict__ dinv,
                         uint32_t* __restrict__ adjp) {
    int idx = blockIdx.x * 256 + threadIdx.x;   // NN*SLOT threads
    int n = idx >> 7, p = idx & (SLOT - 1);
    int cnt = (int)(pk[n] & 0xFFFFu); if (cnt > SLOT) cnt = SLOT;
    int pad = (cnt + 31) & ~31;
    if (p < cnt) {
        uint32_t e = adjp[idx];
        int other = (int)(e & 0xFFFFu);
        float a = ASC * dinv[n] * dinv[other];
        if (e >> 31) a = -a;
        U32H2 t; t.u = (unsigned)other; t.h.y = (_Float16)a;
        adjp[idx] = t.u;
    } else if (p < pad) {
        adjp[idx] = 0u;                          // weight 0 -> contributes nothing
    }
}

// pack 4 consecutive lanes' (USC-scaled) values into fp8x4, lanes lane%4==0 store
static __device__ __forceinline__ void store_u8(uint32_t* __restrict__ u8, int n, int lane, float su) {
    float v1 = __shfl_down(su, 1, 64);
    float v2 = __shfl_down(su, 2, 64);
    float v3 = __shfl_down(su, 3, 64);
    if ((lane & 3) == 0) {
        int p0 = __builtin_amdgcn_cvt_pk_fp8_f32(su, v1, 0, false);
        int p1 = __builtin_amdgcn_cvt_pk_fp8_f32(v2, v3, p0, true);
        u8[n * 16 + (lane >> 2)] = (uint32_t)p1;
    }
}

// ---- opening: x = relu(K1*xn); u0 = KN1*x (f16 + fp8); co = KNc*x ----
__launch_bounds__(256)
__global__ void k_open_u(const float* __restrict__ xn, const float* __restrict__ K1T,
                         const float* __restrict__ KN1T, const float* __restrict__ KNcT,
                         _Float16* __restrict__ u0, uint32_t* __restrict__ u8,
                         float* __restrict__ co) {
    __shared__ float sK1T[NIN * C];
    __shared__ float sKT[C * C];
    __shared__ float sKc[C * C];
    for (int idx = threadIdx.x; idx < NIN * C; idx += 256) sK1T[idx] = K1T[idx];
    for (int idx = threadIdx.x; idx < C * C; idx += 256) { sKT[idx] = KN1T[idx]; sKc[idx] = KNcT[idx]; }
    __syncthreads();
    int wv = threadIdx.x >> 6, lane = threadIdx.x & 63;
    int n = blockIdx.x * 4 + wv;
    float acc = 0.f;
#pragma unroll
    for (int i = 0; i < NIN; i++)
        acc = fmaf(sK1T[i * C + lane], xn[i * NN + n], acc);
    float xr = fmaxf(acc, 0.f);
    float ua = 0.f, oc = 0.f;
    for (int i = 0; i < C; i++) {
        float xi = __shfl(xr, i, 64);
        ua = fmaf(sKT[i * C + lane], xi, ua);
        oc = fmaf(sKc[i * C + lane], xi, oc);
    }
    u0[(size_t)n * C + lane] = (_Float16)ua;
    store_u8(u8, n, lane, ua * USC);
    co[(size_t)n * C + lane] = oc;
}

#define ACCR(WW, QQ, A0, A1, A2, A3, U0, U1, U2, U3) {                        \
    U32H2 aw; aw.u = (WW);                                                    \
    float a_ = (float)aw.h.y;                                                 \
    f32x2 lo_ = __builtin_amdgcn_cvt_pk_f32_fp8((int)(QQ), false);            \
    f32x2 hi_ = __builtin_amdgcn_cvt_pk_f32_fp8((int)(QQ), true);             \
    A0 = fmaf(a_, fmaxf(a_ * ((U0) - lo_.x), 0.f), A0);                       \
    A1 = fmaf(a_, fmaxf(a_ * ((U1) - lo_.y), 0.f), A1);                       \
    A2 = fmaf(a_, fmaxf(a_ * ((U2) - hi_.x), 0.f), A2);                       \
    A3 = fmaf(a_, fmaxf(a_ * ((U3) - hi_.y), 0.f), A3);                       \
}

// ---- two-node interleaved gather core (round-15, verified) ----
#define GATHER2_BODY(PKA, ADJP, U8R)                                          \
    uint32_t unqA = (U8R)[nA * 16 + li];                                      \
    uint32_t unqB = (U8R)[nB * 16 + li];                                      \
    f32x2 alo = __builtin_amdgcn_cvt_pk_f32_fp8((int)unqA, false);            \
    f32x2 ahi = __builtin_amdgcn_cvt_pk_f32_fp8((int)unqA, true);             \
    f32x2 blo = __builtin_amdgcn_cvt_pk_f32_fp8((int)unqB, false);            \
    f32x2 bhi = __builtin_amdgcn_cvt_pk_f32_fp8((int)unqB, true);             \
    float uA0 = alo.x, uA1 = alo.y, uA2 = ahi.x, uA3 = ahi.y;                 \
    float uB0 = blo.x, uB1 = blo.y, uB2 = bhi.x, uB3 = bhi.y;                 \
    int degA = (int)((PKA)[nA] & 0xFFFFu); if (degA > SLOT) degA = SLOT;      \
    int degB = (int)((PKA)[nB] & 0xFFFFu); if (degB > SLOT) degB = SLOT;      \
    int padA = (degA + 31) & ~31, padB = (degB + 31) & ~31;                   \
    int baseA = nA << 7, baseB = nB << 7;                                     \
    int maxPad = padA > padB ? padA : padB;                                   \
    float aA0 = 0.f, aA1 = 0.f, aA2 = 0.f, aA3 = 0.f;                         \
    float aB0 = 0.f, aB1 = 0.f, aB2 = 0.f, aB3 = 0.f;                         \
    for (int c0 = 0; c0 < maxPad; c0 += 32) {                                 \
        uint32_t wA[8], qA[8], wB[8], qB[8];                                  \
        bool dA = c0 < padA, dB = c0 < padB;                                  \
        if (dA) {                                                             \
            _Pragma("unroll")                                                 \
            for (int r = 0; r < 8; r++) wA[r] = (ADJP)[baseA + c0 + r * 4 + g]; \
        }                                                                     \
        if (dB) {                                                             \
            _Pragma("unroll")                                                 \
            for (int r = 0; r < 8; r++) wB[r] = (ADJP)[baseB + c0 + r * 4 + g]; \
        }                                                                     \
        if (dA) {                                                             \
            _Pragma("unroll")                                                 \
            for (int r = 0; r < 8; r++) qA[r] = (U8R)[(wA[r] & 0xFFFFu) * 16 + li]; \
        }                                                                     \
        if (dB) {                                                             \
            _Pragma("unroll")                                                 \
            for (int r = 0; r < 8; r++) qB[r] = (U8R)[(wB[r] & 0xFFFFu) * 16 + li]; \
        }                                                                     \
        if (dA) {                                                             \
            _Pragma("unroll")                                                 \
            for (int r = 0; r < 8; r++) ACCR(wA[r], qA[r], aA0, aA1, aA2, aA3, uA0, uA1, uA2, uA3) \
        }                                                                     \
        if (dB) {                                                             \
            _Pragma("unroll")                                                 \
            for (int r = 0; r < 8; r++) ACCR(wB[r], qB[r], aB0, aB1, aB2, aB3, uB0, uB1, uB2, uB3) \
        }                                                                     \
    }                                                                         \
    aA0 += __shfl_xor(aA0, 16, 64); aA0 += __shfl_xor(aA0, 32, 64);           \
    aA1 += __shfl_xor(aA1, 16, 64); aA1 += __shfl_xor(aA1, 32, 64);           \
    aA2 += __shfl_xor(aA2, 16, 64); aA2 += __shfl_xor(aA2, 32, 64);           \
    aA3 += __shfl_xor(aA3, 16, 64); aA3 += __shfl_xor(aA3, 32, 64);           \
    aB0 += __shfl_xor(aB0, 16, 64); aB0 += __shfl_xor(aB0, 32, 64);           \
    aB1 += __shfl_xor(aB1, 16, 64); aB1 += __shfl_xor(aB1, 32, 64);           \
    aB2 += __shfl_xor(aB2, 16, 64); aB2 += __shfl_xor(aB2, 32, 64);           \
    aB3 += __shfl_xor(aB3, 16, 64); aB3 += __shfl_xor(aB3, 32, 64);           \
    float rA0 = __shfl(aA0, lane >> 2, 64), rA1 = __shfl(aA1, lane >> 2, 64); \
    float rA2 = __shfl(aA2, lane >> 2, 64), rA3 = __shfl(aA3, lane >> 2, 64); \
    float rB0 = __shfl(aB0, lane >> 2, 64), rB1 = __shfl(aB1, lane >> 2, 64); \
    float rB2 = __shfl(aB2, lane >> 2, 64), rB3 = __shfl(aB3, lane >> 2, 64); \
    float sA_lane = (lane & 2) ? ((lane & 1) ? rA3 : rA2)                     \
                               : ((lane & 1) ? rA1 : rA0);                    \
    float sB_lane = (lane & 2) ? ((lane & 1) ? rB3 : rB2)                     \
                               : ((lane & 1) ? rB1 : rB0);

// ---- layers 0..2 fused: s = gather; unext = ucur - c*M2*s (f16+fp8); sacc (+)= s ----
__launch_bounds__(256)
__global__ void k_gather_upd(const unsigned* __restrict__ pk, const uint32_t* __restrict__ adjp,
                             const uint32_t* __restrict__ u8r, const _Float16* __restrict__ ucur,
                             const float* __restrict__ M2s, float* __restrict__ sacc,
                             _Float16* __restrict__ unext, uint32_t* __restrict__ u8w, int beta) {
    __shared__ float sM[C * C];
    for (int idx = threadIdx.x; idx < C * C; idx += 256) sM[idx] = M2s[idx];
    __syncthreads();
    int wv = threadIdx.x >> 6, lane = threadIdx.x & 63;
    int g = lane >> 4, li = lane & 15;
    int nA = (blockIdx.x * 4 + wv) * 2;   // 6250 blocks * 4 waves * 2 nodes = 50000
    int nB = nA + 1;
    GATHER2_BODY(pk, adjp, u8r)
    float duA = 0.f, duB = 0.f;
#pragma unroll
    for (int p = 0; p < C; p++) {
        float m = sM[p * C + lane];
        duA = fmaf(m, __shfl(sA_lane, p, 64), duA);
        duB = fmaf(m, __shfl(sB_lane, p, 64), duB);
    }
    float unewA = (float)ucur[(size_t)nA * C + lane] - (DTH / SDIV) * duA;
    float unewB = (float)ucur[(size_t)nB * C + lane] - (DTH / SDIV) * duB;
    unext[(size_t)nA * C + lane] = (_Float16)unewA;
    unext[(size_t)nB * C + lane] = (_Float16)unewB;
    store_u8(u8w, nA, lane, unewA * USC);
    store_u8(u8w, nB, lane, unewB * USC);
    size_t ixA = (size_t)nA * C + lane, ixB = (size_t)nB * C + lane;
    sacc[ixA] = beta ? (sacc[ixA] + sA_lane) : sA_lane;
    sacc[ixB] = beta ? (sacc[ixB] + sB_lane) : sB_lane;
}

// ---- final layer fused: stot = sacc + s; out = log_softmax(co - c*KM*stot) ----
__launch_bounds__(256)
__global__ void k_gather_close(const unsigned* __restrict__ pk, const uint32_t* __restrict__ adjp,
                               const uint32_t* __restrict__ u8r, const float* __restrict__ KMs,
                               const float* __restrict__ sacc, const float* __restrict__ co,
                               float* __restrict__ out) {
    __shared__ float sKM[C * C];
    for (int idx = threadIdx.x; idx < C * C; idx += 256) sKM[idx] = KMs[idx];
    __syncthreads();
    int wv = threadIdx.x >> 6, lane = threadIdx.x & 63;
    int g = lane >> 4, li = lane & 15;
    int nA = (blockIdx.x * 4 + wv) * 2;
    int nB = nA + 1;
    GATHER2_BODY(pk, adjp, u8r)
    float stotA = sA_lane + sacc[(size_t)nA * C + lane];
    float stotB = sB_lane + sacc[(size_t)nB * C + lane];
    float dxA = 0.f, dxB = 0.f;
#pragma unroll
    for (int p = 0; p < C; p++) {
        float m = sKM[p * C + lane];
        dxA = fmaf(m, __shfl(stotA, p, 64), dxA);
        dxB = fmaf(m, __shfl(stotB, p, 64), dxB);
    }
    float oA = co[(size_t)nA * C + lane] - (DTH / SDIV) * dxA;
    float oB = co[(size_t)nB * C + lane] - (DTH / SDIV) * dxB;
    float mA = oA, mB = oB;
#pragma unroll
    for (int off2 = 32; off2; off2 >>= 1) {
        mA = fmaxf(mA, __shfl_xor(mA, off2, 64));
        mB = fmaxf(mB, __shfl_xor(mB, off2, 64));
    }
    float sumA = expf(oA - mA), sumB = expf(oB - mB);
#pragma unroll
    for (int off2 = 32; off2; off2 >>= 1) {
        sumA += __shfl_xor(sumA, off2, 64);
        sumB += __shfl_xor(sumB, off2, 64);
    }
    out[(size_t)nA * C + lane] = oA - mA - logf(sumA);
    out[(size_t)nB * C + lane] = oB - mB - logf(sumB);
}

extern "C" void kernel_launch(void* const* d_in, const int* in_sizes, int n_in,
                              void* d_out, int out_size, void* d_ws, size_t ws_size,
                              hipStream_t stream) {
    (void)in_sizes; (void)n_in; (void)out_size; (void)ws_size;
    const float* xn   = (const float*)d_in[0];
    const int* iInd   = (const int*)d_in[1];
    const int* jInd   = (const int*)d_in[2];
    // d_in[3] = n_nodes scalar (fixed 50000)
    const float* K1   = (const float*)d_in[4];
    const float* KN1  = (const float*)d_in[5];
    const float* KNc  = (const float*)d_in[6];
    float* out = (float*)d_out;

    char* base = (char*)d_ws;
    size_t off = 0;
    auto alloc = [&](size_t bytes) { char* p = base + off; off = (off + bytes + 255) & ~(size_t)255; return p; };
    float* KN1T = (float*)alloc(C * C * 4);
    float* KNcT = (float*)alloc(C * C * 4);
    float* K1T  = (float*)alloc(NIN * C * 4);
    float* M2s  = (float*)alloc(C * C * 4);
    float* KMs  = (float*)alloc(C * C * 4);
    int* gcur   = (int*)alloc(NB2 * 4);
    unsigned* pk = (unsigned*)alloc(NN * 4);
    float* dinv = (float*)alloc(NN * 4);
    float* co   = (float*)alloc((size_t)NN * C * 4);       // 12.8 MB
    float* sacc = (float*)alloc((size_t)NN * C * 4);       // 12.8 MB
    _Float16* ua = (_Float16*)alloc((size_t)NN * C * 2);   // 6.4 MB
    _Float16* ub = (_Float16*)alloc((size_t)NN * C * 2);   // 6.4 MB
    uint32_t* u8a = (uint32_t*)alloc((size_t)NN * 16 * 4); // 3.2 MB
    uint32_t* u8b = (uint32_t*)alloc((size_t)NN * 16 * 4); // 3.2 MB
    uint32_t* stg = (uint32_t*)alloc((size_t)NB2 * CAP * 4);  // 16.8 MB
    uint32_t* adjp = (uint32_t*)alloc((size_t)NN * SLOT * 4); // 25.6 MB

    // prolog: two-phase binned CSR build (device atomics ~0.3M vs 3.2M)
    k_setup<<<1, 256, 0, stream>>>(KN1, KNc, K1, KN1T, KNcT, K1T, M2s, KMs, gcur);
    k_binA<<<ABLK, 256, 0, stream>>>(iInd, jInd, gcur, stg);
    k_binB<<<NB2, 1024, 0, stream>>>(gcur, stg, pk, adjp);
    k_dinv<<<(NN + 255) / 256, 256, 0, stream>>>(pk, dinv);
    k_weight<<<(NN * SLOT) / 256, 256, 0, stream>>>(pk, dinv, adjp);

    // opening: u0 (f16 + fp8) and co = KNc*x0
    k_open_u<<<NN / 4, 256, 0, stream>>>(xn, K1T, KN1T, KNcT, ua, u8a, co);

    const int GB = NN / 8;    // 6250 blocks, two nodes per wave
    k_gather_upd<<<GB, 256, 0, stream>>>(pk, adjp, u8a, ua, M2s, sacc, ub, u8b, 0);
    k_gather_upd<<<GB, 256, 0, stream>>>(pk, adjp, u8b, ub, M2s, sacc, ua, u8a, 1);
    k_gather_upd<<<GB, 256, 0, stream>>>(pk, adjp, u8a, ua, M2s, sacc, ub, u8b, 1);
    k_gather_close<<<GB, 256, 0, stream>>>(pk, adjp, u8b, KMs, sacc, co, out);
}